// Round 13
// baseline (181.396 us; speedup 1.0000x reference)
//
#include <hip/hip_runtime.h>

#define D 2048
#define M 512

// Tuned NS coefficients, equioscillation on sv interval [0.48,1.52]:
// step1 -> delta 0.2188, step2 -> 0.03633, step3 -> 0.00099
#define CA1 1.7509363f
#define CB1 0.5353890f
#define CA2 1.5424421f
#define CB2 0.5060067f
#define CA3 1.5011558f
#define CB3 0.5001653f

typedef unsigned short u16;
typedef unsigned int u32;
typedef __attribute__((ext_vector_type(8))) short bf16x8;
typedef __attribute__((ext_vector_type(4))) float f32x4;

__device__ inline u16 f2bf(float f) {
    union { float f; unsigned u; } v; v.f = f;
    unsigned r = v.u + 0x7fffu + ((v.u >> 16) & 1u);  // RNE
    return (u16)(r >> 16);
}
__device__ inline float bf2f(u16 h) {
    union { float f; unsigned u; } v; v.u = ((unsigned)h) << 16;
    return v.f;
}

// per-wave K-range fragment MACs into acc pair (split-bf16 3-MFMA scheme)
__device__ inline void mm_ks(const u16* __restrict__ aHi,
                             const u16* __restrict__ aLo, int lda,
                             const u16* __restrict__ bHi,
                             const u16* __restrict__ bLo, int ldb,
                             int K, int lm, int lq, f32x4& a1, f32x4& a2) {
    const u16* ah = aHi + (size_t)lm * lda + lq * 8;
    const u16* al = aLo + (size_t)lm * lda + lq * 8;
    const u16* bh = bHi + (size_t)lm * ldb + lq * 8;
    const u16* bl = bLo + (size_t)lm * ldb + lq * 8;
    #pragma unroll 4
    for (int k = 0; k < K; k += 32) {
        const bf16x8 fah = *(const bf16x8*)(ah + k);
        const bf16x8 fal = *(const bf16x8*)(al + k);
        const bf16x8 fbh = *(const bf16x8*)(bh + k);
        const bf16x8 fbl = *(const bf16x8*)(bl + k);
        a1 = __builtin_amdgcn_mfma_f32_16x16x32_bf16(fah, fbh, a1, 0, 0, 0);
        a2 = __builtin_amdgcn_mfma_f32_16x16x32_bf16(fah, fbl, a2, 0, 0, 0);
        a2 = __builtin_amdgcn_mfma_f32_16x16x32_bf16(fal, fbh, a2, 0, 0, 0);
    }
}

// 32x32 tile of U·V per 512-thread block: 8 waves = 4 quadrants x 2 K-halves.
__device__ inline void tile32(const u16* __restrict__ Uh, const u16* __restrict__ Ul, int lda,
                              const u16* __restrict__ Vh, const u16* __restrict__ Vl, int ldb,
                              int K, int i0, int j0, int t, float* red,
                              float val[2], int row[2], int col[2]) {
    const int w = t >> 6, lane = t & 63;
    const int lm = lane & 15, lq = lane >> 4;
    const int q = w >> 1, kh = w & 1;
    const int qi = q >> 1, qj = q & 1;
    const int Kh = K >> 1;
    const size_t ko = (size_t)kh * Kh;
    f32x4 a1 = {0.f, 0.f, 0.f, 0.f}, a2 = {0.f, 0.f, 0.f, 0.f};
    mm_ks(Uh + (size_t)(i0 + 16 * qi) * lda + ko, Ul + (size_t)(i0 + 16 * qi) * lda + ko, lda,
          Vh + (size_t)(j0 + 16 * qj) * ldb + ko, Vl + (size_t)(j0 + 16 * qj) * ldb + ko, ldb,
          Kh, lm, lq, a1, a2);
    const f32x4 s = a1 + a2;
    #pragma unroll
    for (int r = 0; r < 4; ++r) red[w * 256 + (lq * 4 + r) * 16 + lm] = s[r];
    __syncthreads();
    #pragma unroll
    for (int e = 0; e < 2; ++e) {
        const int ee = t + e * 512;
        const int qq = ee >> 8, p = ee & 255;
        val[e] = red[qq * 512 + p] + red[qq * 512 + 256 + p];
        row[e] = i0 + 16 * (qq >> 1) + (p >> 4);
        col[e] = j0 + 16 * (qq & 1) + (p & 15);
    }
}

// LDS swizzle for the fused gram staging
__device__ inline int swz(int c) { return (((c >> 2) ^ c) & 3) << 3; }

// ---- d1: fused transpose + gram, TRIANGULAR (G0 symmetric): 136 upper-tri
// 32x32 tiles, mirror writes. Diagonal blocks (ti==tj) also emit Xhi/Xlo.
__global__ __launch_bounds__(512) void gram_fx(
    const float* __restrict__ X,
    u16* __restrict__ Gh, u16* __restrict__ Gl,
    u16* __restrict__ Ch, u16* __restrict__ Cl,
    u16* __restrict__ Xhi, u16* __restrict__ Xlo) {
    __shared__ __align__(16) char smem[32768];
    u32* LT = (u32*)smem;          // 4 regions of 2048 u32
    float* red = (float*)smem;     // reused for the final reduce

    // unrank upper-triangle tile index
    int rem = blockIdx.x, ti = 0;
    while (rem >= 16 - ti) { rem -= 16 - ti; ++ti; }
    const int tj = ti + rem;
    const int i0 = ti * 32, j0 = tj * 32;
    const bool emitX = (ti == tj);

    const int t = threadIdx.x;
    const int w = t >> 6, lane = t & 63;
    const int lm = lane & 15, lq = lane >> 4;
    const int q = w >> 1, kh = w & 1;
    const int qi = q >> 1, qj = q & 1;

    const int r = t >> 3;            // 0..63 (k within chunk)
    const int c4 = (t & 7) * 4;      // 0..28 (col within stripe)

    const float* pa = X + (size_t)r * M + i0 + c4;
    const float* pb = X + (size_t)r * M + j0 + c4;
    float4 fA = *(const float4*)pa;
    float4 fB = *(const float4*)pb;

    f32x4 a1 = {0.f, 0.f, 0.f, 0.f}, a2 = {0.f, 0.f, 0.f, 0.f};
    int buf = 0;

    for (int k0 = 0; k0 < D; k0 += 64) {
        u32 pkA[4], pkB[4];
        {
            const float va[4] = {fA.x, fA.y, fA.z, fA.w};
            const float vb[4] = {fB.x, fB.y, fB.z, fB.w};
            #pragma unroll
            for (int e = 0; e < 4; ++e) {
                union { float f; u32 u; } ua, ub, ha, hb;
                ua.f = va[e]; ub.f = vb[e];
                ha.u = ua.u & 0xFFFF0000u;      // truncated hi
                hb.u = ub.u & 0xFFFF0000u;
                pkA[e] = ha.u | f2bf(va[e] - ha.f);
                pkB[e] = hb.u | f2bf(vb[e] - hb.f);
            }
        }
        u32* A0 = LT + (0 * 2 + buf) * 2048;
        u32* B0 = LT + (2 + buf) * 2048;
        #pragma unroll
        for (int e = 0; e < 4; ++e) {
            const int c = c4 + e;
            A0[c * 64 + (r ^ swz(c))] = pkA[e];
            B0[c * 64 + (r ^ swz(c))] = pkB[e];
        }
        if (emitX) {  // row-major bf16 split of X (this block's stripe)
            uint2 hw, lw;
            hw.x = (pkA[0] >> 16) | (pkA[1] & 0xFFFF0000u);
            hw.y = (pkA[2] >> 16) | (pkA[3] & 0xFFFF0000u);
            lw.x = (pkA[0] & 0xFFFFu) | (pkA[1] << 16);
            lw.y = (pkA[2] & 0xFFFFu) | (pkA[3] << 16);
            *(uint2*)(Xhi + (size_t)(k0 + r) * M + i0 + c4) = hw;
            *(uint2*)(Xlo + (size_t)(k0 + r) * M + i0 + c4) = lw;
        }
        __syncthreads();
        if (k0 + 64 < D) {
            fA = *(const float4*)(pa + (size_t)(k0 + 64) * M);
            fB = *(const float4*)(pb + (size_t)(k0 + 64) * M);
        }
        {
            const int ca = 16 * qi + lm, cb = 16 * qj + lm;
            const int kb = kh * 32 + lq * 8;
            const u32* ap = A0 + ca * 64 + (kb ^ swz(ca));
            const u32* bp = B0 + cb * 64 + (kb ^ swz(cb));
            u32 au[8], bu[8];
            *(uint4*)(au) = *(const uint4*)(ap);
            *(uint4*)(au + 4) = *(const uint4*)(ap + 4);
            *(uint4*)(bu) = *(const uint4*)(bp);
            *(uint4*)(bu + 4) = *(const uint4*)(bp + 4);
            u32 ahp[4], alp[4], bhp[4], blp[4];
            #pragma unroll
            for (int e = 0; e < 4; ++e) {
                ahp[e] = (au[2 * e] >> 16) | (au[2 * e + 1] & 0xFFFF0000u);
                alp[e] = (au[2 * e] & 0xFFFFu) | (au[2 * e + 1] << 16);
                bhp[e] = (bu[2 * e] >> 16) | (bu[2 * e + 1] & 0xFFFF0000u);
                blp[e] = (bu[2 * e] & 0xFFFFu) | (bu[2 * e + 1] << 16);
            }
            const bf16x8 fah = *(const bf16x8*)ahp;
            const bf16x8 fal = *(const bf16x8*)alp;
            const bf16x8 fbh = *(const bf16x8*)bhp;
            const bf16x8 fbl = *(const bf16x8*)blp;
            a1 = __builtin_amdgcn_mfma_f32_16x16x32_bf16(fah, fbh, a1, 0, 0, 0);
            a2 = __builtin_amdgcn_mfma_f32_16x16x32_bf16(fah, fbl, a2, 0, 0, 0);
            a2 = __builtin_amdgcn_mfma_f32_16x16x32_bf16(fal, fbh, a2, 0, 0, 0);
        }
        buf ^= 1;
    }

    __syncthreads();
    const f32x4 s = a1 + a2;
    #pragma unroll
    for (int e = 0; e < 4; ++e) red[w * 256 + (lq * 4 + e) * 16 + lm] = s[e];
    __syncthreads();
    #pragma unroll
    for (int e = 0; e < 2; ++e) {
        const int ee = t + e * 512;
        const int qq = ee >> 8, p = ee & 255;
        const float g = red[qq * 512 + p] + red[qq * 512 + 256 + p];
        const int row = i0 + 16 * (qq >> 1) + (p >> 4);
        const int col = j0 + 16 * (qq & 1) + (p & 15);
        const size_t idx = (size_t)row * M + col;
        const size_t idxT = (size_t)col * M + row;
        const u16 gh = f2bf(g);
        const u16 gl = f2bf(g - bf2f(gh));
        Gh[idx] = gh; Gl[idx] = gl;
        Gh[idxT] = gh; Gl[idxT] = gl;
        const float c = (row == col ? CA1 : 0.0f) - CB1 * g;
        const u16 ch = f2bf(c);
        const u16 cl = f2bf(c - bf2f(ch));
        Ch[idx] = ch; Cl[idx] = cl;
        Ch[idxT] = ch; Cl[idxT] = cl;
    }
}

// ---- plain M-space mm: O = U·V. grid 256 x 512 thr, 32x32 tile/block.
__global__ __launch_bounds__(512) void mm32(
    const u16* __restrict__ Uh, const u16* __restrict__ Ul,
    const u16* __restrict__ Vh, const u16* __restrict__ Vl,
    u16* __restrict__ Oh, u16* __restrict__ Ol) {
    __shared__ float red[2048];
    const int i0 = (blockIdx.x >> 4) * 32, j0 = (blockIdx.x & 15) * 32;
    float val[2]; int row[2], col[2];
    tile32(Uh, Ul, M, Vh, Vl, M, 512, i0, j0, threadIdx.x, red, val, row, col);
    #pragma unroll
    for (int e = 0; e < 2; ++e) {
        const size_t idx = (size_t)row[e] * M + col[e];
        const u16 h = f2bf(val[e]);
        Oh[idx] = h; Ol[idx] = f2bf(val[e] - bf2f(h));
    }
}

// ---- dual M-space mm: job0: O0=U0·V0, job1: O1=U1·V1. grid 512 x 512 thr.
__global__ __launch_bounds__(512) void dual32(
    const u16* __restrict__ U0h, const u16* __restrict__ U0l,
    const u16* __restrict__ V0h, const u16* __restrict__ V0l,
    u16* __restrict__ O0h, u16* __restrict__ O0l,
    const u16* __restrict__ U1h, const u16* __restrict__ U1l,
    const u16* __restrict__ V1h, const u16* __restrict__ V1l,
    u16* __restrict__ O1h, u16* __restrict__ O1l) {
    __shared__ float red[2048];
    const int job = blockIdx.x >> 8, tile = blockIdx.x & 255;
    const int i0 = (tile >> 4) * 32, j0 = (tile & 15) * 32;
    const u16* Uh = job ? U1h : U0h;
    const u16* Ul = job ? U1l : U0l;
    const u16* Vh = job ? V1h : V0h;
    const u16* Vl = job ? V1l : V0l;
    u16* Oh = job ? O1h : O0h;
    u16* Ol = job ? O1l : O0l;
    float val[2]; int row[2], col[2];
    tile32(Uh, Ul, M, Vh, Vl, M, 512, i0, j0, threadIdx.x, red, val, row, col);
    #pragma unroll
    for (int e = 0; e < 2; ++e) {
        const size_t idx = (size_t)row[e] * M + col[e];
        const u16 h = f2bf(val[e]);
        Oh[idx] = h; Ol[idx] = f2bf(val[e] - bf2f(h));
    }
}

// ---- poly step: W=U·V; P = cA*Ge + cB*Se + cC*W; store P (opt), C = a*I - b*P.
__global__ __launch_bounds__(512) void poly32(
    const u16* __restrict__ Uh, const u16* __restrict__ Ul,
    const u16* __restrict__ Vh, const u16* __restrict__ Vl,
    const u16* __restrict__ Geh, const u16* __restrict__ Gel,
    const u16* __restrict__ Seh, const u16* __restrict__ Sel,
    u16* __restrict__ Ph, u16* __restrict__ Pl,
    u16* __restrict__ Ch, u16* __restrict__ Cl,
    const float cA, const float cB, const float cC,
    const float a, const float b, const int writeP) {
    __shared__ float red[2048];
    const int i0 = (blockIdx.x >> 4) * 32, j0 = (blockIdx.x & 15) * 32;
    float val[2]; int row[2], col[2];
    tile32(Uh, Ul, M, Vh, Vl, M, 512, i0, j0, threadIdx.x, red, val, row, col);
    #pragma unroll
    for (int e = 0; e < 2; ++e) {
        const size_t idx = (size_t)row[e] * M + col[e];
        const float p = cA * (bf2f(Geh[idx]) + bf2f(Gel[idx]))
                      + cB * (bf2f(Seh[idx]) + bf2f(Sel[idx]))
                      + cC * val[e];
        if (writeP) {
            const u16 h = f2bf(p);
            Ph[idx] = h; Pl[idx] = f2bf(p - bf2f(h));
        }
        const float c = (row[e] == col[e] ? a : 0.0f) - b * p;
        const u16 h2 = f2bf(c);
        Ch[idx] = h2; Cl[idx] = f2bf(c - bf2f(h2));
    }
}

// ---- d5: blocks 0..255: C3-poly (W2 = G1·S1); blocks 256..1279: Y = X·B2.
__global__ __launch_bounds__(512) void poly_y32(
    const u16* __restrict__ G1h, const u16* __restrict__ G1l,
    const u16* __restrict__ S1h, const u16* __restrict__ S1l,
    u16* __restrict__ C3h, u16* __restrict__ C3l,
    const u16* __restrict__ Xhi, const u16* __restrict__ Xlo,
    const u16* __restrict__ B2h, const u16* __restrict__ B2l,
    u16* __restrict__ Yh, u16* __restrict__ Yl) {
    __shared__ float red[2048];
    const int t = threadIdx.x;
    float val[2]; int row[2], col[2];
    if (blockIdx.x < 256) {
        const int i0 = ((int)blockIdx.x >> 4) * 32, j0 = ((int)blockIdx.x & 15) * 32;
        tile32(G1h, G1l, M, S1h, S1l, M, 512, i0, j0, t, red, val, row, col);
        #pragma unroll
        for (int e = 0; e < 2; ++e) {
            const size_t idx = (size_t)row[e] * M + col[e];
            const float p = (CA2 * CA2) * (bf2f(G1h[idx]) + bf2f(G1l[idx]))
                          + (-2.0f * CA2 * CB2) * (bf2f(S1h[idx]) + bf2f(S1l[idx]))
                          + (CB2 * CB2) * val[e];
            const float c = (row[e] == col[e] ? CA3 : 0.0f) - CB3 * p;
            const u16 h = f2bf(c);
            C3h[idx] = h; C3l[idx] = f2bf(c - bf2f(h));
        }
    } else {
        const int tile = (int)blockIdx.x - 256;       // 0..1023 = 64 i x 16 j
        const int i0 = (tile >> 4) * 32, j0 = (tile & 15) * 32;
        tile32(Xhi, Xlo, M, B2h, B2l, M, 512, i0, j0, t, red, val, row, col);
        #pragma unroll
        for (int e = 0; e < 2; ++e) {
            const size_t idx = (size_t)row[e] * M + col[e];
            const u16 h = f2bf(val[e]);
            Yh[idx] = h; Yl[idx] = f2bf(val[e] - bf2f(h));
        }
    }
}

// ---- d6: out = Y·C3 (fp32). 32x32 tile/block, 4 full-K quadrant waves.
__global__ __launch_bounds__(256) void final32(
    const u16* __restrict__ Yh, const u16* __restrict__ Yl,
    const u16* __restrict__ Bh, const u16* __restrict__ Bl,
    float* __restrict__ out) {
    const int t = threadIdx.x;
    const int i0 = (blockIdx.x >> 4) * 32, j0 = (blockIdx.x & 15) * 32;
    const int w = t >> 6, lane = t & 63;
    const int lm = lane & 15, lq = lane >> 4;
    const int qi = w >> 1, qj = w & 1;
    f32x4 a1 = {0.f, 0.f, 0.f, 0.f}, a2 = {0.f, 0.f, 0.f, 0.f};
    mm_ks(Yh + (size_t)(i0 + 16 * qi) * M, Yl + (size_t)(i0 + 16 * qi) * M, M,
          Bh + (size_t)(j0 + 16 * qj) * M, Bl + (size_t)(j0 + 16 * qj) * M, M,
          512, lm, lq, a1, a2);
    const f32x4 acc = a1 + a2;
    float* o = out + (size_t)(i0 + 16 * qi + lq * 4) * M + j0 + 16 * qj + lm;
    #pragma unroll
    for (int r = 0; r < 4; ++r) o[(size_t)r * M] = acc[r];
}

extern "C" void kernel_launch(void* const* d_in, const int* in_sizes, int n_in,
                              void* d_out, int out_size, void* d_ws, size_t ws_size,
                              hipStream_t stream) {
    const float* Xin = (const float*)d_in[0];
    float* out = (float*)d_out;
    u16* w = (u16*)d_ws;

    u16* Xhi  = w;                   // D*M = 1048576 each
    u16* Xlo  = w + 1048576u;
    u16* q = w + 2097152u;           // M*M = 262144 each below
    u16* G0h = q;            u16* G0l = q + 262144u;
    u16* Sh  = q + 524288u;  u16* Sl  = q + 786432u;
    u16* G1h = q + 1048576u; u16* G1l = q + 1310720u;
    u16* S1h = q + 1572864u; u16* S1l = q + 1835008u;
    u16* C1h = q + 2097152u; u16* C1l = q + 2359296u;
    u16* C2h = q + 2621440u; u16* C2l = q + 2883584u;
    u16* C3h = q + 3145728u; u16* C3l = q + 3407872u;
    u16* B2h = q + 3670016u; u16* B2l = q + 3932160u;
    u16* Yh  = q + 4194304u;         // D*M each
    u16* Yl  = Yh + 1048576u;

    // d1: fused transpose + triangular gram: G0, C1 (mirrored), Xhi/Xlo
    gram_fx<<<136, 512, 0, stream>>>(Xin, G0h, G0l, C1h, C1l, Xhi, Xlo);
    // d2: S = G0^2
    mm32<<<256, 512, 0, stream>>>(G0h, G0l, G0h, G0l, Sh, Sl);
    // d3: G1 = CA1^2 G0 - 2 CA1 CB1 S + CB1^2 (G0·S) ; C2 = CA2 I - CB2 G1
    poly32<<<256, 512, 0, stream>>>(G0h, G0l, Sh, Sl, G0h, G0l, Sh, Sl,
                                    G1h, G1l, C2h, C2l,
                                    CA1 * CA1, -2.0f * CA1 * CB1, CB1 * CB1,
                                    CA2, CB2, 1);
    // d4: S1 = G1^2  ||  B2 = C1·C2
    dual32<<<512, 512, 0, stream>>>(G1h, G1l, G1h, G1l, S1h, S1l,
                                    C1h, C1l, C2h, C2l, B2h, B2l);
    // d5: C3 from G2-poly  ||  Y = X·B2
    poly_y32<<<1280, 512, 0, stream>>>(G1h, G1l, S1h, S1l, C3h, C3l,
                                       Xhi, Xlo, B2h, B2l, Yh, Yl);
    // d6: out = Y·C3
    final32<<<1024, 256, 0, stream>>>(Yh, Yl, C3h, C3l, out);
}

// Round 14
// 157.410 us; speedup vs baseline: 1.1524x; 1.1524x over previous
//
#include <hip/hip_runtime.h>

#define D 2048
#define M 512

// Tuned NS coefficients, equioscillation on sv interval [0.48,1.52]:
// step1 -> delta 0.2188, step2 -> 0.03633, step3 -> 0.00099
#define CA1 1.7509363f
#define CB1 0.5353890f
#define CA2 1.5424421f
#define CB2 0.5060067f
#define CA3 1.5011558f
#define CB3 0.5001653f

typedef unsigned short u16;
typedef unsigned int u32;
typedef __attribute__((ext_vector_type(8))) short bf16x8;
typedef __attribute__((ext_vector_type(4))) float f32x4;

__device__ inline u16 f2bf(float f) {
    union { float f; unsigned u; } v; v.f = f;
    unsigned r = v.u + 0x7fffu + ((v.u >> 16) & 1u);  // RNE
    return (u16)(r >> 16);
}
__device__ inline float bf2f(u16 h) {
    union { float f; unsigned u; } v; v.u = ((unsigned)h) << 16;
    return v.f;
}

// per-wave K-range fragment MACs into acc pair (split-bf16 3-MFMA scheme)
__device__ inline void mm_ks(const u16* __restrict__ aHi,
                             const u16* __restrict__ aLo, int lda,
                             const u16* __restrict__ bHi,
                             const u16* __restrict__ bLo, int ldb,
                             int K, int lm, int lq, f32x4& a1, f32x4& a2) {
    const u16* ah = aHi + (size_t)lm * lda + lq * 8;
    const u16* al = aLo + (size_t)lm * lda + lq * 8;
    const u16* bh = bHi + (size_t)lm * ldb + lq * 8;
    const u16* bl = bLo + (size_t)lm * ldb + lq * 8;
    #pragma unroll 8
    for (int k = 0; k < K; k += 32) {
        const bf16x8 fah = *(const bf16x8*)(ah + k);
        const bf16x8 fal = *(const bf16x8*)(al + k);
        const bf16x8 fbh = *(const bf16x8*)(bh + k);
        const bf16x8 fbl = *(const bf16x8*)(bl + k);
        a1 = __builtin_amdgcn_mfma_f32_16x16x32_bf16(fah, fbh, a1, 0, 0, 0);
        a2 = __builtin_amdgcn_mfma_f32_16x16x32_bf16(fah, fbl, a2, 0, 0, 0);
        a2 = __builtin_amdgcn_mfma_f32_16x16x32_bf16(fal, fbh, a2, 0, 0, 0);
    }
}

// 32x32 tile of U·V per 512-thread block: 8 waves = 4 quadrants x 2 K-halves.
__device__ inline void tile32(const u16* __restrict__ Uh, const u16* __restrict__ Ul, int lda,
                              const u16* __restrict__ Vh, const u16* __restrict__ Vl, int ldb,
                              int K, int i0, int j0, int t, float* red,
                              float val[2], int row[2], int col[2]) {
    const int w = t >> 6, lane = t & 63;
    const int lm = lane & 15, lq = lane >> 4;
    const int q = w >> 1, kh = w & 1;
    const int qi = q >> 1, qj = q & 1;
    const int Kh = K >> 1;
    const size_t ko = (size_t)kh * Kh;
    f32x4 a1 = {0.f, 0.f, 0.f, 0.f}, a2 = {0.f, 0.f, 0.f, 0.f};
    mm_ks(Uh + (size_t)(i0 + 16 * qi) * lda + ko, Ul + (size_t)(i0 + 16 * qi) * lda + ko, lda,
          Vh + (size_t)(j0 + 16 * qj) * ldb + ko, Vl + (size_t)(j0 + 16 * qj) * ldb + ko, ldb,
          Kh, lm, lq, a1, a2);
    const f32x4 s = a1 + a2;
    #pragma unroll
    for (int r = 0; r < 4; ++r) red[w * 256 + (lq * 4 + r) * 16 + lm] = s[r];
    __syncthreads();
    #pragma unroll
    for (int e = 0; e < 2; ++e) {
        const int ee = t + e * 512;
        const int qq = ee >> 8, p = ee & 255;
        val[e] = red[qq * 512 + p] + red[qq * 512 + 256 + p];
        row[e] = i0 + 16 * (qq >> 1) + (p >> 4);
        col[e] = j0 + 16 * (qq & 1) + (p & 15);
    }
}

// LDS swizzle for the fused gram staging
__device__ inline int swz(int c) { return (((c >> 2) ^ c) & 3) << 3; }

// ---- d1: fused transpose + gram: G0 = X^T X from X fp32 directly.
// 256 blocks x 512 thr. 128-k chunks (16 iters, 2 MFMA-triples/iter), LDS
// transposed [c][k^swz(c)] double-buffered (64 KB). j0==0 blocks also emit
// Xhi/Xlo row-major. Emits G0 hi/lo and C1 = CA1*I - CB1*G0.
__global__ __launch_bounds__(512) void gram_fx(
    const float* __restrict__ X,
    u16* __restrict__ Gh, u16* __restrict__ Gl,
    u16* __restrict__ Ch, u16* __restrict__ Cl,
    u16* __restrict__ Xhi, u16* __restrict__ Xlo) {
    __shared__ __align__(16) char smem[65536];
    u32* LT = (u32*)smem;          // 4 regions of 4096 u32: A:buf, B:2+buf
    float* red = (float*)smem;     // reused for the final reduce

    const int i0 = (blockIdx.x >> 4) * 32, j0 = (blockIdx.x & 15) * 32;
    const int t = threadIdx.x;
    const int w = t >> 6, lane = t & 63;
    const int lm = lane & 15, lq = lane >> 4;
    const int q = w >> 1, kh = w & 1;
    const int qi = q >> 1, qj = q & 1;
    const bool emitX = (j0 == 0);

    const int r = t >> 3;            // 0..63 (k within chunk, +64 for 2nd row)
    const int c4 = (t & 7) * 4;      // 0..28 (col within stripe)

    const float* pa = X + (size_t)r * M + i0 + c4;
    const float* pb = X + (size_t)r * M + j0 + c4;
    float4 fA0 = *(const float4*)pa;
    float4 fA1 = *(const float4*)(pa + (size_t)64 * M);
    float4 fB0 = *(const float4*)pb;
    float4 fB1 = *(const float4*)(pb + (size_t)64 * M);

    f32x4 a1 = {0.f, 0.f, 0.f, 0.f}, a2 = {0.f, 0.f, 0.f, 0.f};
    int buf = 0;

    for (int k0 = 0; k0 < D; k0 += 128) {
        u32 pkA0[4], pkA1[4], pkB0[4], pkB1[4];
        {
            const float va0[4] = {fA0.x, fA0.y, fA0.z, fA0.w};
            const float va1[4] = {fA1.x, fA1.y, fA1.z, fA1.w};
            const float vb0[4] = {fB0.x, fB0.y, fB0.z, fB0.w};
            const float vb1[4] = {fB1.x, fB1.y, fB1.z, fB1.w};
            #pragma unroll
            for (int e = 0; e < 4; ++e) {
                union { float f; u32 u; } u0, u1, u2, u3, h0, h1, h2, h3;
                u0.f = va0[e]; u1.f = va1[e]; u2.f = vb0[e]; u3.f = vb1[e];
                h0.u = u0.u & 0xFFFF0000u;  // truncated hi
                h1.u = u1.u & 0xFFFF0000u;
                h2.u = u2.u & 0xFFFF0000u;
                h3.u = u3.u & 0xFFFF0000u;
                pkA0[e] = h0.u | f2bf(va0[e] - h0.f);
                pkA1[e] = h1.u | f2bf(va1[e] - h1.f);
                pkB0[e] = h2.u | f2bf(vb0[e] - h2.f);
                pkB1[e] = h3.u | f2bf(vb1[e] - h3.f);
            }
        }
        u32* A0 = LT + buf * 4096;
        u32* B0 = LT + (2 + buf) * 4096;
        #pragma unroll
        for (int e = 0; e < 4; ++e) {
            const int c = c4 + e;
            const int rk = r ^ swz(c);
            A0[c * 128 + rk] = pkA0[e];
            A0[c * 128 + rk + 64] = pkA1[e];
            B0[c * 128 + rk] = pkB0[e];
            B0[c * 128 + rk + 64] = pkB1[e];
        }
        if (emitX) {  // row-major bf16 split of X (this block's stripe)
            uint2 hw, lw;
            hw.x = (pkA0[0] >> 16) | (pkA0[1] & 0xFFFF0000u);
            hw.y = (pkA0[2] >> 16) | (pkA0[3] & 0xFFFF0000u);
            lw.x = (pkA0[0] & 0xFFFFu) | (pkA0[1] << 16);
            lw.y = (pkA0[2] & 0xFFFFu) | (pkA0[3] << 16);
            *(uint2*)(Xhi + (size_t)(k0 + r) * M + i0 + c4) = hw;
            *(uint2*)(Xlo + (size_t)(k0 + r) * M + i0 + c4) = lw;
            hw.x = (pkA1[0] >> 16) | (pkA1[1] & 0xFFFF0000u);
            hw.y = (pkA1[2] >> 16) | (pkA1[3] & 0xFFFF0000u);
            lw.x = (pkA1[0] & 0xFFFFu) | (pkA1[1] << 16);
            lw.y = (pkA1[2] & 0xFFFFu) | (pkA1[3] << 16);
            *(uint2*)(Xhi + (size_t)(k0 + r + 64) * M + i0 + c4) = hw;
            *(uint2*)(Xlo + (size_t)(k0 + r + 64) * M + i0 + c4) = lw;
        }
        __syncthreads();
        if (k0 + 128 < D) {
            fA0 = *(const float4*)(pa + (size_t)(k0 + 128) * M);
            fA1 = *(const float4*)(pa + (size_t)(k0 + 192) * M);
            fB0 = *(const float4*)(pb + (size_t)(k0 + 128) * M);
            fB1 = *(const float4*)(pb + (size_t)(k0 + 192) * M);
        }
        #pragma unroll
        for (int ks = 0; ks < 64; ks += 32) {
            const int ca = 16 * qi + lm, cb = 16 * qj + lm;
            const int kb = kh * 64 + ks + lq * 8;
            const u32* ap = A0 + ca * 128 + (kb ^ swz(ca));
            const u32* bp = B0 + cb * 128 + (kb ^ swz(cb));
            u32 au[8], bu[8];
            *(uint4*)(au) = *(const uint4*)(ap);
            *(uint4*)(au + 4) = *(const uint4*)(ap + 4);
            *(uint4*)(bu) = *(const uint4*)(bp);
            *(uint4*)(bu + 4) = *(const uint4*)(bp + 4);
            u32 ahp[4], alp[4], bhp[4], blp[4];
            #pragma unroll
            for (int e = 0; e < 4; ++e) {
                ahp[e] = (au[2 * e] >> 16) | (au[2 * e + 1] & 0xFFFF0000u);
                alp[e] = (au[2 * e] & 0xFFFFu) | (au[2 * e + 1] << 16);
                bhp[e] = (bu[2 * e] >> 16) | (bu[2 * e + 1] & 0xFFFF0000u);
                blp[e] = (bu[2 * e] & 0xFFFFu) | (bu[2 * e + 1] << 16);
            }
            const bf16x8 fah = *(const bf16x8*)ahp;
            const bf16x8 fal = *(const bf16x8*)alp;
            const bf16x8 fbh = *(const bf16x8*)bhp;
            const bf16x8 fbl = *(const bf16x8*)blp;
            a1 = __builtin_amdgcn_mfma_f32_16x16x32_bf16(fah, fbh, a1, 0, 0, 0);
            a2 = __builtin_amdgcn_mfma_f32_16x16x32_bf16(fah, fbl, a2, 0, 0, 0);
            a2 = __builtin_amdgcn_mfma_f32_16x16x32_bf16(fal, fbh, a2, 0, 0, 0);
        }
        buf ^= 1;
    }

    __syncthreads();
    const f32x4 s = a1 + a2;
    #pragma unroll
    for (int e = 0; e < 4; ++e) red[w * 256 + (lq * 4 + e) * 16 + lm] = s[e];
    __syncthreads();
    #pragma unroll
    for (int e = 0; e < 2; ++e) {
        const int ee = t + e * 512;
        const int qq = ee >> 8, p = ee & 255;
        const float g = red[qq * 512 + p] + red[qq * 512 + 256 + p];
        const int row = i0 + 16 * (qq >> 1) + (p >> 4);
        const int col = j0 + 16 * (qq & 1) + (p & 15);
        const size_t idx = (size_t)row * M + col;
        u16 h = f2bf(g);
        Gh[idx] = h; Gl[idx] = f2bf(g - bf2f(h));
        const float c = (row == col ? CA1 : 0.0f) - CB1 * g;
        h = f2bf(c);
        Ch[idx] = h; Cl[idx] = f2bf(c - bf2f(h));
    }
}

// ---- plain M-space mm: O = U·V. grid 256 x 512 thr, 32x32 tile/block.
__global__ __launch_bounds__(512) void mm32(
    const u16* __restrict__ Uh, const u16* __restrict__ Ul,
    const u16* __restrict__ Vh, const u16* __restrict__ Vl,
    u16* __restrict__ Oh, u16* __restrict__ Ol) {
    __shared__ float red[2048];
    const int i0 = (blockIdx.x >> 4) * 32, j0 = (blockIdx.x & 15) * 32;
    float val[2]; int row[2], col[2];
    tile32(Uh, Ul, M, Vh, Vl, M, 512, i0, j0, threadIdx.x, red, val, row, col);
    #pragma unroll
    for (int e = 0; e < 2; ++e) {
        const size_t idx = (size_t)row[e] * M + col[e];
        const u16 h = f2bf(val[e]);
        Oh[idx] = h; Ol[idx] = f2bf(val[e] - bf2f(h));
    }
}

// ---- dual M-space mm: job0: O0=U0·V0, job1: O1=U1·V1. grid 512 x 512 thr.
__global__ __launch_bounds__(512) void dual32(
    const u16* __restrict__ U0h, const u16* __restrict__ U0l,
    const u16* __restrict__ V0h, const u16* __restrict__ V0l,
    u16* __restrict__ O0h, u16* __restrict__ O0l,
    const u16* __restrict__ U1h, const u16* __restrict__ U1l,
    const u16* __restrict__ V1h, const u16* __restrict__ V1l,
    u16* __restrict__ O1h, u16* __restrict__ O1l) {
    __shared__ float red[2048];
    const int job = blockIdx.x >> 8, tile = blockIdx.x & 255;
    const int i0 = (tile >> 4) * 32, j0 = (tile & 15) * 32;
    const u16* Uh = job ? U1h : U0h;
    const u16* Ul = job ? U1l : U0l;
    const u16* Vh = job ? V1h : V0h;
    const u16* Vl = job ? V1l : V0l;
    u16* Oh = job ? O1h : O0h;
    u16* Ol = job ? O1l : O0l;
    float val[2]; int row[2], col[2];
    tile32(Uh, Ul, M, Vh, Vl, M, 512, i0, j0, threadIdx.x, red, val, row, col);
    #pragma unroll
    for (int e = 0; e < 2; ++e) {
        const size_t idx = (size_t)row[e] * M + col[e];
        const u16 h = f2bf(val[e]);
        Oh[idx] = h; Ol[idx] = f2bf(val[e] - bf2f(h));
    }
}

// ---- poly step: W=U·V; P = cA*Ge + cB*Se + cC*W; store P (opt), C = a*I - b*P.
__global__ __launch_bounds__(512) void poly32(
    const u16* __restrict__ Uh, const u16* __restrict__ Ul,
    const u16* __restrict__ Vh, const u16* __restrict__ Vl,
    const u16* __restrict__ Geh, const u16* __restrict__ Gel,
    const u16* __restrict__ Seh, const u16* __restrict__ Sel,
    u16* __restrict__ Ph, u16* __restrict__ Pl,
    u16* __restrict__ Ch, u16* __restrict__ Cl,
    const float cA, const float cB, const float cC,
    const float a, const float b, const int writeP) {
    __shared__ float red[2048];
    const int i0 = (blockIdx.x >> 4) * 32, j0 = (blockIdx.x & 15) * 32;
    float val[2]; int row[2], col[2];
    tile32(Uh, Ul, M, Vh, Vl, M, 512, i0, j0, threadIdx.x, red, val, row, col);
    #pragma unroll
    for (int e = 0; e < 2; ++e) {
        const size_t idx = (size_t)row[e] * M + col[e];
        const float p = cA * (bf2f(Geh[idx]) + bf2f(Gel[idx]))
                      + cB * (bf2f(Seh[idx]) + bf2f(Sel[idx]))
                      + cC * val[e];
        if (writeP) {
            const u16 h = f2bf(p);
            Ph[idx] = h; Pl[idx] = f2bf(p - bf2f(h));
        }
        const float c = (row[e] == col[e] ? a : 0.0f) - b * p;
        const u16 h2 = f2bf(c);
        Ch[idx] = h2; Cl[idx] = f2bf(c - bf2f(h2));
    }
}

// ---- d7: out = X·B (fp32). 32x32 tile/block, 4 full-K quadrant waves.
__global__ __launch_bounds__(256) void final32(
    const u16* __restrict__ Xhi, const u16* __restrict__ Xlo,
    const u16* __restrict__ Bh, const u16* __restrict__ Bl,
    float* __restrict__ out) {
    const int t = threadIdx.x;
    const int i0 = (blockIdx.x >> 4) * 32, j0 = (blockIdx.x & 15) * 32;
    const int w = t >> 6, lane = t & 63;
    const int lm = lane & 15, lq = lane >> 4;
    const int qi = w >> 1, qj = w & 1;
    f32x4 a1 = {0.f, 0.f, 0.f, 0.f}, a2 = {0.f, 0.f, 0.f, 0.f};
    mm_ks(Xhi + (size_t)(i0 + 16 * qi) * M, Xlo + (size_t)(i0 + 16 * qi) * M, M,
          Bh + (size_t)(j0 + 16 * qj) * M, Bl + (size_t)(j0 + 16 * qj) * M, M,
          512, lm, lq, a1, a2);
    const f32x4 acc = a1 + a2;
    float* o = out + (size_t)(i0 + 16 * qi + lq * 4) * M + j0 + 16 * qj + lm;
    #pragma unroll
    for (int r = 0; r < 4; ++r) o[(size_t)r * M] = acc[r];
}

extern "C" void kernel_launch(void* const* d_in, const int* in_sizes, int n_in,
                              void* d_out, int out_size, void* d_ws, size_t ws_size,
                              hipStream_t stream) {
    const float* Xin = (const float*)d_in[0];
    float* out = (float*)d_out;
    u16* w = (u16*)d_ws;

    u16* Xhi  = w;                   // D*M = 1048576 each
    u16* Xlo  = w + 1048576u;
    u16* q = w + 2097152u;           // M*M = 262144 each below
    u16* G0h = q;            u16* G0l = q + 262144u;
    u16* Sh  = q + 524288u;  u16* Sl  = q + 786432u;
    u16* G1h = q + 1048576u; u16* G1l = q + 1310720u;
    u16* S1h = q + 1572864u; u16* S1l = q + 1835008u;
    u16* C1h = q + 2097152u; u16* C1l = q + 2359296u;
    u16* C2h = q + 2621440u; u16* C2l = q + 2883584u;
    u16* C3h = q + 3145728u; u16* C3l = q + 3407872u;
    u16* B2h = q + 3670016u; u16* B2l = q + 3932160u;
    u16* B3h = q + 4194304u; u16* B3l = q + 4456448u;

    // d1: fused transpose + gram: G0, C1, Xhi/Xlo
    gram_fx<<<256, 512, 0, stream>>>(Xin, G0h, G0l, C1h, C1l, Xhi, Xlo);
    // d2: S = G0^2
    mm32<<<256, 512, 0, stream>>>(G0h, G0l, G0h, G0l, Sh, Sl);
    // d3: G1 = CA1^2 G0 - 2 CA1 CB1 S + CB1^2 (G0·S) ; C2 = CA2 I - CB2 G1
    poly32<<<256, 512, 0, stream>>>(G0h, G0l, Sh, Sl, G0h, G0l, Sh, Sl,
                                    G1h, G1l, C2h, C2l,
                                    CA1 * CA1, -2.0f * CA1 * CB1, CB1 * CB1,
                                    CA2, CB2, 1);
    // d4: S1 = G1^2  ||  B2 = C1·C2
    dual32<<<512, 512, 0, stream>>>(G1h, G1l, G1h, G1l, S1h, S1l,
                                    C1h, C1l, C2h, C2l, B2h, B2l);
    // d5: G2-poly -> C3 only
    poly32<<<256, 512, 0, stream>>>(G1h, G1l, S1h, S1l, G1h, G1l, S1h, S1l,
                                    nullptr, nullptr, C3h, C3l,
                                    CA2 * CA2, -2.0f * CA2 * CB2, CB2 * CB2,
                                    CA3, CB3, 0);
    // d6: B3 = B2·C3
    mm32<<<256, 512, 0, stream>>>(B2h, B2l, C3h, C3l, B3h, B3l);
    // d7: out = X·B3
    final32<<<1024, 256, 0, stream>>>(Xhi, Xlo, B3h, B3l, out);
}